// Round 12
// baseline (138.437 us; speedup 1.0000x reference)
//
#include <hip/hip_runtime.h>
#include <hip/hip_fp16.h>
#include <math.h>

#define K_NB   32
#define C_IN   64
#define C_OUT  128
#define KP     96     // packed pooled row: 64 x-max + 3 rel-xyz + 29 zeros (fp16)
#define TILE   128    // rows per gemm block
#define BN_EPS 1e-5f

typedef _Float16 f16x8 __attribute__((ext_vector_type(8)));
typedef float    f32x4 __attribute__((ext_vector_type(4)));
typedef float    f32x2 __attribute__((ext_vector_type(2)));

__device__ __forceinline__ unsigned pk(float a, float b) {
    __half2 h = __floats2half2_rn(a, b);
    return *reinterpret_cast<unsigned*>(&h);
}

// packed fp16 max on the 32-bit register view (v_pk_max_f16)
__device__ __forceinline__ unsigned pkmax(unsigned a, unsigned b) {
    unsigned d;
    asm volatile("v_pk_max_f16 %0, %1, %2" : "=v"(d) : "v"(a), "v"(b));
    return d;
}

// bit-view of cvt_pkrtz result (its return type is an __fp16 ext-vector)
using pkrtz_t = decltype(__builtin_amdgcn_cvt_pkrtz(0.f, 0.f));
__device__ __forceinline__ unsigned h2u(pkrtz_t v) {
    union { pkrtz_t h; unsigned u; } c; c.h = v; return c.u;
}

// decode one dword of 4 fp8 (e4m3) -> two packed-fp16 dwords (exact)
__device__ __forceinline__ void fp8x4_to_h2x2(unsigned d, unsigned& lo, unsigned& hi) {
    f32x2 a = __builtin_amdgcn_cvt_pk_f32_fp8((int)d, false);
    f32x2 b = __builtin_amdgcn_cvt_pk_f32_fp8((int)d, true);
    lo = h2u(__builtin_amdgcn_cvt_pkrtz(a.x, a.y));
    hi = h2u(__builtin_amdgcn_cvt_pkrtz(b.x, b.y));
}

// ---------------------------------------------------------------------------
// zero n floats (fallback path only; zeroes gsum replicas + barrier counter)
// ---------------------------------------------------------------------------
__global__ __launch_bounds__(256) void sa_zero(float* __restrict__ g, int n)
{
    for (int i = threadIdx.x; i < n; i += 256) g[i] = 0.f;
}

// ---------------------------------------------------------------------------
// x (f32) -> fp8 e4m3 copy in ws; block 0 zeros gsum replicas + barrier cnt
// (ng includes the counter word: 0.0f bits == 0u)
// ---------------------------------------------------------------------------
__global__ __launch_bounds__(256) void sa_cvt(
    const float4* __restrict__ x4, uint4* __restrict__ xq, int n16,
    float* __restrict__ gsum, int ng)
{
    if (blockIdx.x == 0)
        for (int i = threadIdx.x; i < ng; i += 256) gsum[i] = 0.f;
    for (int i = blockIdx.x * blockDim.x + threadIdx.x; i < n16;
         i += gridDim.x * blockDim.x) {
        float4 v0 = x4[4*i+0], v1 = x4[4*i+1], v2 = x4[4*i+2], v3 = x4[4*i+3];
        int w0 = 0, w1 = 0, w2 = 0, w3 = 0;
        w0 = __builtin_amdgcn_cvt_pk_fp8_f32(v0.x, v0.y, w0, false);
        w0 = __builtin_amdgcn_cvt_pk_fp8_f32(v0.z, v0.w, w0, true);
        w1 = __builtin_amdgcn_cvt_pk_fp8_f32(v1.x, v1.y, w1, false);
        w1 = __builtin_amdgcn_cvt_pk_fp8_f32(v1.z, v1.w, w1, true);
        w2 = __builtin_amdgcn_cvt_pk_fp8_f32(v2.x, v2.y, w2, false);
        w2 = __builtin_amdgcn_cvt_pk_fp8_f32(v2.z, v2.w, w2, true);
        w3 = __builtin_amdgcn_cvt_pk_fp8_f32(v3.x, v3.y, w3, false);
        w3 = __builtin_amdgcn_cvt_pk_fp8_f32(v3.z, v3.w, w3, true);
        xq[i] = make_uint4((unsigned)w0, (unsigned)w1, (unsigned)w2, (unsigned)w3);
    }
}

// ---------------------------------------------------------------------------
// pool (R11-proven): fp8 gather, decode fp8->fp16, packed-fp16 max; writes
// n_p (f32) and the packed 96-half pooled row tile-locally in the h region.
// ---------------------------------------------------------------------------
__global__ __launch_bounds__(256) void sa_pool_h(
    const float* __restrict__ p, const uint2* __restrict__ xq2,
    const int* __restrict__ idx, const int* __restrict__ knn,
    float* __restrict__ np_out, float* __restrict__ hbuf)
{
    const int lane = threadIdx.x & 63;
    const int m    = blockIdx.x * 4 + (threadIdx.x >> 6);

    int kidx = 0;
    if (lane < K_NB) kidx = knn[m * K_NB + lane];

    unsigned mx0 = 0xFC00FC00u, mx1 = 0xFC00FC00u;   // (-inf,-inf) fp16
    unsigned mx2 = 0xFC00FC00u, mx3 = 0xFC00FC00u;

    const int sub = lane & 7;            // 8B slice within the 64B fp8 row
    #pragma unroll
    for (int i = 0; i < 4; ++i) {
        int nb = __shfl(kidx, i * 8 + (lane >> 3));      // 8 rows in flight/inst
        uint2 u = xq2[(size_t)nb * 8 + sub];
        unsigned h01, h23, h45, h67;
        fp8x4_to_h2x2(u.x, h01, h23);
        fp8x4_to_h2x2(u.y, h45, h67);
        mx0 = pkmax(mx0, h01);
        mx1 = pkmax(mx1, h23);
        mx2 = pkmax(mx2, h45);
        mx3 = pkmax(mx3, h67);
    }
    // butterfly over lane bits 3,4,5 (row-group merge), fp16 packed max
    #pragma unroll
    for (int off = 8; off <= 32; off <<= 1) {
        mx0 = pkmax(mx0, (unsigned)__shfl_xor((int)mx0, off));
        mx1 = pkmax(mx1, (unsigned)__shfl_xor((int)mx1, off));
        mx2 = pkmax(mx2, (unsigned)__shfl_xor((int)mx2, off));
        mx3 = pkmax(mx3, (unsigned)__shfl_xor((int)mx3, off));
    }

    // xyz max-pool (fp32 p, mostly L2-resident)
    float px = -INFINITY, py = -INFINITY, pz = -INFINITY;
    if (lane < K_NB) {
        const float* pp = p + (size_t)kidx * 3;
        px = pp[0]; py = pp[1]; pz = pp[2];
    }
    #pragma unroll
    for (int off = 32; off >= 1; off >>= 1) {
        px = fmaxf(px, __shfl_xor(px, off));
        py = fmaxf(py, __shfl_xor(py, off));
        pz = fmaxf(pz, __shfl_xor(pz, off));
    }

    const int s = idx[m];
    const float npx = p[(size_t)s*3+0];
    const float npy = p[(size_t)s*3+1];
    const float npz = p[(size_t)s*3+2];
    if (lane < 3) np_out[(size_t)m*3 + lane] = (lane == 0) ? npx : (lane == 1 ? npy : npz);

    const int tile = m >> 7, rl = m & (TILE - 1);
    __half* rowh = (__half*)(hbuf + (size_t)tile * TILE * C_OUT) + rl * KP;
    if (lane < 8) {
        *(uint4*)(rowh + lane * 8) = make_uint4(mx0, mx1, mx2, mx3);
    } else if (lane == 8) {
        *(uint4*)(rowh + 64) = make_uint4(pk(px-npx, py-npy), pk(pz-npz, 0.f), 0u, 0u);
    } else if (lane < 12) {
        *(uint4*)(rowh + 64 + (lane - 8) * 8) = make_uint4(0u, 0u, 0u, 0u);
    }
}

// f32-gather fallback (ws too small for fp8 x copy); same packed output
__global__ __launch_bounds__(256) void sa_pool_f(
    const float* __restrict__ p, const float* __restrict__ x,
    const int* __restrict__ idx, const int* __restrict__ knn,
    float* __restrict__ np_out, float* __restrict__ hbuf)
{
    const int lane = threadIdx.x & 63;
    const int m    = blockIdx.x * 4 + (threadIdx.x >> 6);
    int kidx = 0;
    if (lane < K_NB) kidx = knn[m * K_NB + lane];
    float xmax = -INFINITY;
    #pragma unroll
    for (int k = 0; k < K_NB; ++k) {
        int nb = __shfl(kidx, k);
        xmax = fmaxf(xmax, x[(size_t)nb * C_IN + lane]);
    }
    float px = -INFINITY, py = -INFINITY, pz = -INFINITY;
    if (lane < K_NB) {
        const float* pp = p + (size_t)kidx * 3;
        px = pp[0]; py = pp[1]; pz = pp[2];
    }
    #pragma unroll
    for (int off = 32; off >= 1; off >>= 1) {
        px = fmaxf(px, __shfl_xor(px, off));
        py = fmaxf(py, __shfl_xor(py, off));
        pz = fmaxf(pz, __shfl_xor(pz, off));
    }
    const int s = idx[m];
    const float npx = p[(size_t)s*3], npy = p[(size_t)s*3+1], npz = p[(size_t)s*3+2];
    if (lane < 3) np_out[(size_t)m*3 + lane] = (lane == 0) ? npx : (lane == 1 ? npy : npz);

    const int tile = m >> 7, rl = m & (TILE - 1);
    __half* rowh = (__half*)(hbuf + (size_t)tile * TILE * C_OUT) + rl * KP;
    if (lane < 8) {
        float v[8];
        #pragma unroll
        for (int j = 0; j < 8; ++j) v[j] = __shfl(xmax, lane * 8 + j);
        *(uint4*)(rowh + lane * 8) =
            make_uint4(pk(v[0],v[1]), pk(v[2],v[3]), pk(v[4],v[5]), pk(v[6],v[7]));
    } else if (lane == 8) {
        *(uint4*)(rowh + 64) = make_uint4(pk(px-npx, py-npy), pk(pz-npz, 0.f), 0u, 0u);
    } else if (lane < 12) {
        *(uint4*)(rowh + 64 + (lane - 8) * 8) = make_uint4(0u, 0u, 0u, 0u);
    }
}

// ---------------------------------------------------------------------------
// MFMA GEMM + BN + ReLU fused via software grid barrier, single h write.
// Phase A: acc = pooled_fp16 @ Wt + b in registers; column stats ->
//          replicated gsum atomics; arrive at device-scope counter.
// Spin (t==0) until all nblk blocks arrived.  All 512 blocks co-resident:
// 36 KB LDS -> >=4 blocks/CU by LDS; even 2 blocks/CU capacity == grid.
// Phase B: scale/shift from gsum (agent-scope atomic loads — XCD L2s are
//          not coherent, G16); apply BN+ReLU to registers; single store.
// All A-reads precede the barrier; all h-writes follow it (alias-race-free).
// ---------------------------------------------------------------------------
__global__ __launch_bounds__(256) void sa_gemm_bn(
    const float* __restrict__ W, const float* __restrict__ bias,
    const float* __restrict__ gamma, const float* __restrict__ beta,
    float* __restrict__ h, float* __restrict__ gsum, unsigned* __restrict__ cnt,
    float* __restrict__ no_out, unsigned rep_mask, int rep, int M, unsigned nblk)
{
    __shared__ __half Wt[C_OUT][128];    // 32 KB (12/16 chunks used, swizzled)
    __shared__ float reds[4][C_OUT];     // 2 KB; reused as sc[] in phase B
    __shared__ float redq[4][C_OUT];     // 2 KB; reused as sh[] in phase B

    const int t    = threadIdx.x;
    const int wave = t >> 6, lane = t & 63;
    const int l15  = lane & 15, lg = lane >> 4;
    const int m0   = blockIdx.x * TILE;

    // stage Wt[c][k]: k<64 -> W[3+k][c]; k<67 -> W[k-64][c]; else 0
    for (int e = t; e < C_OUT * KP; e += 256) {
        const int c = e & 127, kk = e >> 7;
        float w = 0.f;
        if (kk < C_IN)          w = W[(size_t)(3 + kk) * C_OUT + c];
        else if (kk < C_IN + 3) w = W[(size_t)(kk - C_IN) * C_OUT + c];
        Wt[c][(((kk >> 3) ^ (c & 7)) << 3) | (kk & 7)] = __float2half(w);
    }

    // hoist all A fragments (fp16 region overwritten only after the barrier)
    const __half* tb = (const __half*)(h + (size_t)blockIdx.x * TILE * C_OUT);
    f16x8 A[2][3];
    #pragma unroll
    for (int rt = 0; rt < 2; ++rt) {
        const int rl = wave * 32 + rt * 16 + l15;
        #pragma unroll
        for (int ks = 0; ks < 3; ++ks)
            A[rt][ks] = *(const f16x8*)(tb + (size_t)rl * KP + ks * 32 + lg * 8);
    }
    __syncthreads();

    f32x4 acc[2][8];
    #pragma unroll
    for (int ct = 0; ct < 8; ++ct) {
        const float bc = bias[ct * 16 + l15];
        acc[0][ct] = (f32x4){bc, bc, bc, bc};
        acc[1][ct] = (f32x4){bc, bc, bc, bc};
    }
    #pragma unroll
    for (int ks = 0; ks < 3; ++ks) {
        #pragma unroll
        for (int ct = 0; ct < 8; ++ct) {
            const int c  = ct * 16 + l15;
            const int kc = ks * 4 + lg;
            const f16x8 wf = *(const f16x8*)&Wt[c][((kc ^ (c & 7)) << 3)];
            acc[0][ct] = __builtin_amdgcn_mfma_f32_16x16x32_f16(A[0][ks], wf, acc[0][ct], 0, 0, 0);
            acc[1][ct] = __builtin_amdgcn_mfma_f32_16x16x32_f16(A[1][ks], wf, acc[1][ct], 0, 0, 0);
        }
    }

    // column stats: per-thread over 8 rows, cross-lg shfl, LDS, atomics
    #pragma unroll
    for (int ct = 0; ct < 8; ++ct) {
        float s = 0.f, q = 0.f;
        #pragma unroll
        for (int rt = 0; rt < 2; ++rt)
            #pragma unroll
            for (int r = 0; r < 4; ++r) {
                const float v = acc[rt][ct][r];
                s += v; q = fmaf(v, v, q);
            }
        s += __shfl_xor(s, 16); s += __shfl_xor(s, 32);
        q += __shfl_xor(q, 16); q += __shfl_xor(q, 32);
        if (lg == 0) { reds[wave][ct * 16 + l15] = s; redq[wave][ct * 16 + l15] = q; }
    }
    __syncthreads();
    if (t < C_OUT) {
        const float ss = reds[0][t] + reds[1][t] + reds[2][t] + reds[3][t];
        const float qq = redq[0][t] + redq[1][t] + redq[2][t] + redq[3][t];
        float* g = gsum + (size_t)(blockIdx.x & rep_mask) * 2 * C_OUT;
        atomicAdd(&g[t],         ss);
        atomicAdd(&g[C_OUT + t], qq);
    }
    __syncthreads();                       // all this block's atomics issued+drained

    // ---- software grid barrier ----
    if (t == 0) {
        __threadfence();                   // order gsum atomics before arrival
        __hip_atomic_fetch_add(cnt, 1u, __ATOMIC_RELEASE, __HIP_MEMORY_SCOPE_AGENT);
        while (__hip_atomic_load(cnt, __ATOMIC_ACQUIRE, __HIP_MEMORY_SCOPE_AGENT) < nblk) {}
    }
    __syncthreads();

    // scale/shift from final gsum (agent-scope loads bypass stale L2)
    if (t < C_OUT) {
        float s = 0.f, s2 = 0.f;
        for (int r = 0; r < rep; ++r) {
            s  += __hip_atomic_load(&gsum[(size_t)r * 2 * C_OUT + t],
                                    __ATOMIC_RELAXED, __HIP_MEMORY_SCOPE_AGENT);
            s2 += __hip_atomic_load(&gsum[(size_t)r * 2 * C_OUT + C_OUT + t],
                                    __ATOMIC_RELAXED, __HIP_MEMORY_SCOPE_AGENT);
        }
        const float inv_m = 1.0f / (float)M;
        const float mean = s * inv_m;
        const float var  = fmaf(-mean, mean, s2 * inv_m);
        const float sc   = gamma[t] * rsqrtf(var + BN_EPS);
        reds[0][t] = sc;
        redq[0][t] = fmaf(-mean, sc, beta[t]);
    }
    if (blockIdx.x == 0 && t == 0) no_out[0] = (float)M;
    __syncthreads();

    // apply BN + ReLU from registers, single store
    #pragma unroll
    for (int rt = 0; rt < 2; ++rt) {
        #pragma unroll
        for (int ct = 0; ct < 8; ++ct) {
            const int col = ct * 16 + l15;
            const float scv = reds[0][col], shv = redq[0][col];
            #pragma unroll
            for (int r = 0; r < 4; ++r) {
                const int row = m0 + wave * 32 + rt * 16 + lg * 4 + r;
                h[(size_t)row * C_OUT + col] =
                    fmaxf(fmaf(acc[rt][ct][r], scv, shv), 0.f);
            }
        }
    }
}

extern "C" void kernel_launch(void* const* d_in, const int* in_sizes, int n_in,
                              void* d_out, int out_size, void* d_ws, size_t ws_size,
                              hipStream_t stream)
{
    const float* p     = (const float*)d_in[0];
    const float* x     = (const float*)d_in[1];
    // d_in[2] = o (unused)
    const int*   idx   = (const int*)d_in[3];
    const int*   knn   = (const int*)d_in[4];
    const float* W     = (const float*)d_in[5];
    const float* bias  = (const float*)d_in[6];
    const float* gamma = (const float*)d_in[7];
    const float* beta  = (const float*)d_in[8];

    const int N = in_sizes[1] / C_IN;  // 262144
    const int M = in_sizes[3];         // 65536

    float* out    = (float*)d_out;
    float* np_out = out;                                     // [M,3]
    float* h      = out + (size_t)M * 3;                     // [M,128]
    float* no_out = out + (size_t)M * 3 + (size_t)M * C_OUT; // [1]

    const size_t xq_bytes = (size_t)N * C_IN;                // 16 MB fp8 table
    const bool   fp8_path = ws_size >= xq_bytes + 2048;

    const size_t tail = fp8_path ? (ws_size - xq_bytes) : ws_size;
    int rep = 1;
    while (rep < 8 && (size_t)(2 * rep) * 2 * C_OUT * sizeof(float) + 64 <= tail)
        rep <<= 1;

    float*    gsum = fp8_path ? (float*)((char*)d_ws + xq_bytes) : (float*)d_ws;
    unsigned* cnt  = (unsigned*)(gsum + (size_t)rep * 2 * C_OUT);
    const unsigned rep_mask = (unsigned)(rep - 1);
    const unsigned nblk     = (unsigned)(M / TILE);          // 512

    if (fp8_path) {
        uint4* xq = (uint4*)d_ws;
        const int n16 = N * C_IN / 16;
        sa_cvt   <<<2048, 256, 0, stream>>>((const float4*)x, xq, n16,
                                            gsum, rep * 2 * C_OUT + 1);
        sa_pool_h<<<M / 4, 256, 0, stream>>>(p, (const uint2*)d_ws, idx, knn, np_out, h);
    } else {
        sa_zero  <<<1, 256, 0, stream>>>(gsum, rep * 2 * C_OUT + 1);
        sa_pool_f<<<M / 4, 256, 0, stream>>>(p, x, idx, knn, np_out, h);
    }

    sa_gemm_bn<<<nblk, 256, 0, stream>>>(W, bias, gamma, beta, h, gsum, cnt,
                                         no_out, rep_mask, rep, M, nblk);
}

// Round 13
// 105.222 us; speedup vs baseline: 1.3157x; 1.3157x over previous
//
#include <hip/hip_runtime.h>
#include <hip/hip_fp16.h>
#include <math.h>

#define K_NB   32
#define C_IN   64
#define C_OUT  128
#define KP     96     // packed pooled row: 64 x-max + 3 rel-xyz + 29 zeros (fp16)
#define TILE   128    // rows per gemm block
#define BN_EPS 1e-5f

typedef _Float16 f16x8 __attribute__((ext_vector_type(8)));
typedef float    f32x4 __attribute__((ext_vector_type(4)));
typedef float    f32x2 __attribute__((ext_vector_type(2)));

__device__ __forceinline__ unsigned pk(float a, float b) {
    __half2 h = __floats2half2_rn(a, b);
    return *reinterpret_cast<unsigned*>(&h);
}

// packed fp16 max on the 32-bit register view (v_pk_max_f16)
__device__ __forceinline__ unsigned pkmax(unsigned a, unsigned b) {
    unsigned d;
    asm volatile("v_pk_max_f16 %0, %1, %2" : "=v"(d) : "v"(a), "v"(b));
    return d;
}

// bit-view of cvt_pkrtz result (its return type is an __fp16 ext-vector)
using pkrtz_t = decltype(__builtin_amdgcn_cvt_pkrtz(0.f, 0.f));
__device__ __forceinline__ unsigned h2u(pkrtz_t v) {
    union { pkrtz_t h; unsigned u; } c; c.h = v; return c.u;
}

// decode one dword of 4 fp8 (e4m3) -> two packed-fp16 dwords (exact)
__device__ __forceinline__ void fp8x4_to_h2x2(unsigned d, unsigned& lo, unsigned& hi) {
    f32x2 a = __builtin_amdgcn_cvt_pk_f32_fp8((int)d, false);
    f32x2 b = __builtin_amdgcn_cvt_pk_f32_fp8((int)d, true);
    lo = h2u(__builtin_amdgcn_cvt_pkrtz(a.x, a.y));
    hi = h2u(__builtin_amdgcn_cvt_pkrtz(b.x, b.y));
}

// ---------------------------------------------------------------------------
// zero n floats (fallback path only)
// ---------------------------------------------------------------------------
__global__ __launch_bounds__(256) void sa_zero(float* __restrict__ g, int n)
{
    for (int i = threadIdx.x; i < n; i += 256) g[i] = 0.f;
}

// ---------------------------------------------------------------------------
// x (f32) -> fp8 e4m3 copy in ws; block 0 also zeros the BN-stat replicas
// ---------------------------------------------------------------------------
__global__ __launch_bounds__(256) void sa_cvt(
    const float4* __restrict__ x4, uint4* __restrict__ xq, int n16,
    float* __restrict__ gsum, int ng)
{
    if (blockIdx.x == 0)
        for (int i = threadIdx.x; i < ng; i += 256) gsum[i] = 0.f;
    for (int i = blockIdx.x * blockDim.x + threadIdx.x; i < n16;
         i += gridDim.x * blockDim.x) {
        float4 v0 = x4[4*i+0], v1 = x4[4*i+1], v2 = x4[4*i+2], v3 = x4[4*i+3];
        int w0 = 0, w1 = 0, w2 = 0, w3 = 0;
        w0 = __builtin_amdgcn_cvt_pk_fp8_f32(v0.x, v0.y, w0, false);
        w0 = __builtin_amdgcn_cvt_pk_fp8_f32(v0.z, v0.w, w0, true);
        w1 = __builtin_amdgcn_cvt_pk_fp8_f32(v1.x, v1.y, w1, false);
        w1 = __builtin_amdgcn_cvt_pk_fp8_f32(v1.z, v1.w, w1, true);
        w2 = __builtin_amdgcn_cvt_pk_fp8_f32(v2.x, v2.y, w2, false);
        w2 = __builtin_amdgcn_cvt_pk_fp8_f32(v2.z, v2.w, w2, true);
        w3 = __builtin_amdgcn_cvt_pk_fp8_f32(v3.x, v3.y, w3, false);
        w3 = __builtin_amdgcn_cvt_pk_fp8_f32(v3.z, v3.w, w3, true);
        xq[i] = make_uint4((unsigned)w0, (unsigned)w1, (unsigned)w2, (unsigned)w3);
    }
}

// ---------------------------------------------------------------------------
// pool, 2 points per wave: all 8 gather loads issued before any decode
// (doubles memory-level parallelism; the R11 version had only ~4 in flight
// and was latency-bound at ~3.3 TB/s). kidx covers both points via one
// coalesced 64-lane knn load. Packed 96-half rows written tile-locally in h.
// ---------------------------------------------------------------------------
__global__ __launch_bounds__(256) void sa_pool_h(
    const float* __restrict__ p, const uint2* __restrict__ xq2,
    const int* __restrict__ idx, const int* __restrict__ knn,
    float* __restrict__ np_out, float* __restrict__ hbuf)
{
    const int lane = threadIdx.x & 63;
    const int wid  = threadIdx.x >> 6;
    const int m0   = blockIdx.x * 8 + wid * 2;     // this wave: points m0, m0+1
    const int half = lane >> 5;                    // 0 -> m0, 1 -> m0+1
    const int m    = m0 + half;

    // one coalesced load: lanes 0..31 = pt0 neighbors, 32..63 = pt1 neighbors
    const int kidx = knn[m0 * K_NB + lane];

    // ---- issue ALL 8 gather loads (2 pts x 4 row-groups) before decoding ----
    const int sub = lane & 7;                      // 8B slice of the 64B row
    const int g   = lane >> 3;                     // row-group 0..7
    uint2 u[8];
    #pragma unroll
    for (int i = 0; i < 4; ++i) {
        const int nbA = __shfl(kidx, i * 8 + g);          // pt0 rows
        u[i] = xq2[(size_t)nbA * 8 + sub];
    }
    #pragma unroll
    for (int i = 0; i < 4; ++i) {
        const int nbB = __shfl(kidx, 32 + i * 8 + g);     // pt1 rows
        u[4 + i] = xq2[(size_t)nbB * 8 + sub];
    }

    // ---- decode + packed-fp16 max ----
    unsigned mx0 = 0xFC00FC00u, mx1 = 0xFC00FC00u, mx2 = 0xFC00FC00u, mx3 = 0xFC00FC00u;
    unsigned my0 = 0xFC00FC00u, my1 = 0xFC00FC00u, my2 = 0xFC00FC00u, my3 = 0xFC00FC00u;
    #pragma unroll
    for (int i = 0; i < 4; ++i) {
        unsigned h01, h23, h45, h67;
        fp8x4_to_h2x2(u[i].x, h01, h23);
        fp8x4_to_h2x2(u[i].y, h45, h67);
        mx0 = pkmax(mx0, h01); mx1 = pkmax(mx1, h23);
        mx2 = pkmax(mx2, h45); mx3 = pkmax(mx3, h67);
    }
    #pragma unroll
    for (int i = 0; i < 4; ++i) {
        unsigned h01, h23, h45, h67;
        fp8x4_to_h2x2(u[4 + i].x, h01, h23);
        fp8x4_to_h2x2(u[4 + i].y, h45, h67);
        my0 = pkmax(my0, h01); my1 = pkmax(my1, h23);
        my2 = pkmax(my2, h45); my3 = pkmax(my3, h67);
    }
    // merge row-groups: lane bits 3,4,5 (both points' partials live in all lanes)
    #pragma unroll
    for (int off = 8; off <= 32; off <<= 1) {
        mx0 = pkmax(mx0, (unsigned)__shfl_xor((int)mx0, off));
        mx1 = pkmax(mx1, (unsigned)__shfl_xor((int)mx1, off));
        mx2 = pkmax(mx2, (unsigned)__shfl_xor((int)mx2, off));
        mx3 = pkmax(mx3, (unsigned)__shfl_xor((int)mx3, off));
        my0 = pkmax(my0, (unsigned)__shfl_xor((int)my0, off));
        my1 = pkmax(my1, (unsigned)__shfl_xor((int)my1, off));
        my2 = pkmax(my2, (unsigned)__shfl_xor((int)my2, off));
        my3 = pkmax(my3, (unsigned)__shfl_xor((int)my3, off));
    }

    // ---- xyz max-pool: each 32-half reduces its own point ----
    const float* pp = p + (size_t)kidx * 3;
    float px = pp[0], py = pp[1], pz = pp[2];
    #pragma unroll
    for (int off = 16; off >= 1; off >>= 1) {
        px = fmaxf(px, __shfl_xor(px, off));
        py = fmaxf(py, __shfl_xor(py, off));
        pz = fmaxf(pz, __shfl_xor(pz, off));
    }

    const int s = idx[m];
    const float npx = p[(size_t)s*3+0];
    const float npy = p[(size_t)s*3+1];
    const float npz = p[(size_t)s*3+2];
    if (lane < 3)                    np_out[(size_t)m0*3 + lane] = (lane == 0) ? npx : (lane == 1 ? npy : npz);
    else if (lane >= 32 && lane < 35) np_out[(size_t)(m0+1)*3 + (lane-32)] = (lane == 32) ? npx : (lane == 33 ? npy : npz);

    const float rx = px - npx, ry = py - npy, rz = pz - npz;  // per-half values

    const int t0 = m0 >> 7,       rl0 = m0 & (TILE - 1);
    const int t1 = (m0+1) >> 7,   rl1 = (m0+1) & (TILE - 1);
    __half* rowh0 = (__half*)(hbuf + (size_t)t0 * TILE * C_OUT) + rl0 * KP;
    __half* rowh1 = (__half*)(hbuf + (size_t)t1 * TILE * C_OUT) + rl1 * KP;

    if (lane < 8) {                        // pt0 channels (sub = lane)
        *(uint4*)(rowh0 + lane * 8) = make_uint4(mx0, mx1, mx2, mx3);
    } else if (lane < 16) {                // pt1 channels (sub = lane-8)
        *(uint4*)(rowh1 + (lane - 8) * 8) = make_uint4(my0, my1, my2, my3);
    } else if (lane == 16) {               // pt0 xyz+pad (half0 lane -> pt0 rel)
        *(uint4*)(rowh0 + 64) = make_uint4(pk(rx, ry), pk(rz, 0.f), 0u, 0u);
    } else if (lane >= 17 && lane < 20) {  // pt0 zero tail 72..95
        *(uint4*)(rowh0 + 64 + (lane - 16) * 8) = make_uint4(0u, 0u, 0u, 0u);
    } else if (lane == 48) {               // pt1 xyz+pad (half1 lane -> pt1 rel)
        *(uint4*)(rowh1 + 64) = make_uint4(pk(rx, ry), pk(rz, 0.f), 0u, 0u);
    } else if (lane >= 49 && lane < 52) {  // pt1 zero tail 72..95
        *(uint4*)(rowh1 + 64 + (lane - 48) * 8) = make_uint4(0u, 0u, 0u, 0u);
    }
}

// f32-gather fallback (ws too small for fp8 x copy); 1 point/wave, same packing
__global__ __launch_bounds__(256) void sa_pool_f(
    const float* __restrict__ p, const float* __restrict__ x,
    const int* __restrict__ idx, const int* __restrict__ knn,
    float* __restrict__ np_out, float* __restrict__ hbuf)
{
    const int lane = threadIdx.x & 63;
    const int m    = blockIdx.x * 4 + (threadIdx.x >> 6);
    int kidx = 0;
    if (lane < K_NB) kidx = knn[m * K_NB + lane];
    float xmax = -INFINITY;
    #pragma unroll
    for (int k = 0; k < K_NB; ++k) {
        int nb = __shfl(kidx, k);
        xmax = fmaxf(xmax, x[(size_t)nb * C_IN + lane]);
    }
    float px = -INFINITY, py = -INFINITY, pz = -INFINITY;
    if (lane < K_NB) {
        const float* pp = p + (size_t)kidx * 3;
        px = pp[0]; py = pp[1]; pz = pp[2];
    }
    #pragma unroll
    for (int off = 32; off >= 1; off >>= 1) {
        px = fmaxf(px, __shfl_xor(px, off));
        py = fmaxf(py, __shfl_xor(py, off));
        pz = fmaxf(pz, __shfl_xor(pz, off));
    }
    const int s = idx[m];
    const float npx = p[(size_t)s*3], npy = p[(size_t)s*3+1], npz = p[(size_t)s*3+2];
    if (lane < 3) np_out[(size_t)m*3 + lane] = (lane == 0) ? npx : (lane == 1 ? npy : npz);

    const int tile = m >> 7, rl = m & (TILE - 1);
    __half* rowh = (__half*)(hbuf + (size_t)tile * TILE * C_OUT) + rl * KP;
    if (lane < 8) {
        float v[8];
        #pragma unroll
        for (int j = 0; j < 8; ++j) v[j] = __shfl(xmax, lane * 8 + j);
        *(uint4*)(rowh + lane * 8) =
            make_uint4(pk(v[0],v[1]), pk(v[2],v[3]), pk(v[4],v[5]), pk(v[6],v[7]));
    } else if (lane == 8) {
        *(uint4*)(rowh + 64) = make_uint4(pk(px-npx, py-npy), pk(pz-npz, 0.f), 0u, 0u);
    } else if (lane < 12) {
        *(uint4*)(rowh + 64 + (lane - 8) * 8) = make_uint4(0u, 0u, 0u, 0u);
    }
}

// ---------------------------------------------------------------------------
// MFMA GEMM (R9/R11-proven): h[tile,:] = pooled_fp16 @ Wt + b, raw store,
// fused BN partial stats -> replicated gsum atomics.
// ---------------------------------------------------------------------------
__global__ __launch_bounds__(256) void sa_gemm_mfma(
    const float* __restrict__ W, const float* __restrict__ bias,
    float* __restrict__ h, float* __restrict__ gsum, unsigned rep_mask)
{
    __shared__ __half Wt[C_OUT][128];    // 32 KB (12/16 chunks used, swizzled)
    __shared__ float reds[16][C_OUT];    // 8 KB
    __shared__ float redq[16][C_OUT];    // 8 KB

    const int t    = threadIdx.x;
    const int wave = t >> 6, lane = t & 63;
    const int l15  = lane & 15, lg = lane >> 4;
    const int m0   = blockIdx.x * TILE;

    // stage Wt[c][k]: k<64 -> W[3+k][c]; k<67 -> W[k-64][c]; else 0
    for (int e = t; e < C_OUT * KP; e += 256) {
        const int c = e & 127, kk = e >> 7;
        float w = 0.f;
        if (kk < C_IN)          w = W[(size_t)(3 + kk) * C_OUT + c];
        else if (kk < C_IN + 3) w = W[(size_t)(kk - C_IN) * C_OUT + c];
        Wt[c][(((kk >> 3) ^ (c & 7)) << 3) | (kk & 7)] = __float2half(w);
    }

    // hoist all A fragments (fp16 region this block later overwrites)
    const __half* tb = (const __half*)(h + (size_t)blockIdx.x * TILE * C_OUT);
    f16x8 A[2][3];
    #pragma unroll
    for (int rt = 0; rt < 2; ++rt) {
        const int rl = wave * 32 + rt * 16 + l15;
        #pragma unroll
        for (int ks = 0; ks < 3; ++ks)
            A[rt][ks] = *(const f16x8*)(tb + (size_t)rl * KP + ks * 32 + lg * 8);
    }
    __syncthreads();   // Wt staged AND all A reads complete before any store

    f32x4 acc[2][8];
    #pragma unroll
    for (int ct = 0; ct < 8; ++ct) {
        const float bc = bias[ct * 16 + l15];
        acc[0][ct] = (f32x4){bc, bc, bc, bc};
        acc[1][ct] = (f32x4){bc, bc, bc, bc};
    }
    #pragma unroll
    for (int ks = 0; ks < 3; ++ks) {
        #pragma unroll
        for (int ct = 0; ct < 8; ++ct) {
            const int c  = ct * 16 + l15;
            const int kc = ks * 4 + lg;
            const f16x8 wf = *(const f16x8*)&Wt[c][((kc ^ (c & 7)) << 3)];
            acc[0][ct] = __builtin_amdgcn_mfma_f32_16x16x32_f16(A[0][ks], wf, acc[0][ct], 0, 0, 0);
            acc[1][ct] = __builtin_amdgcn_mfma_f32_16x16x32_f16(A[1][ks], wf, acc[1][ct], 0, 0, 0);
        }
    }

    // store raw h + per-thread column stats
    float s8[8], q8[8];
    #pragma unroll
    for (int ct = 0; ct < 8; ++ct) { s8[ct] = 0.f; q8[ct] = 0.f; }
    #pragma unroll
    for (int rt = 0; rt < 2; ++rt) {
        #pragma unroll
        for (int ct = 0; ct < 8; ++ct) {
            const int col = ct * 16 + l15;
            #pragma unroll
            for (int r = 0; r < 4; ++r) {
                const int row = m0 + wave * 32 + rt * 16 + lg * 4 + r;
                const float v = acc[rt][ct][r];
                h[(size_t)row * C_OUT + col] = v;
                s8[ct] += v;
                q8[ct]  = fmaf(v, v, q8[ct]);
            }
        }
    }
    #pragma unroll
    for (int ct = 0; ct < 8; ++ct) {
        reds[wave * 4 + lg][ct * 16 + l15] = s8[ct];
        redq[wave * 4 + lg][ct * 16 + l15] = q8[ct];
    }
    __syncthreads();
    if (t < C_OUT) {
        float ss = 0.f, qq = 0.f;
        #pragma unroll
        for (int i = 0; i < 16; ++i) { ss += reds[i][t]; qq += redq[i][t]; }
        float* g = gsum + (size_t)(blockIdx.x & rep_mask) * 2 * C_OUT;
        atomicAdd(&g[t],         ss);
        atomicAdd(&g[C_OUT + t], qq);
    }
}

// ---------------------------------------------------------------------------
// finalize fused into BN+ReLU: every block reduces the rep replicas (tiny),
// computes scale/shift in LDS, then grid-strides the in-place affine.
// Block 0 writes n_o.
// ---------------------------------------------------------------------------
__global__ __launch_bounds__(256) void sa_bnrelu_fin(
    float* __restrict__ h, const float* __restrict__ gsum,
    const float* __restrict__ gamma, const float* __restrict__ beta,
    float* __restrict__ no_out, int M, int rep)
{
    __shared__ float sc[C_OUT], sh[C_OUT];
    const int t = threadIdx.x;
    if (t < C_OUT) {
        float s = 0.f, s2 = 0.f;
        for (int r = 0; r < rep; ++r) {
            s  += gsum[(size_t)r * 2 * C_OUT + t];
            s2 += gsum[(size_t)r * 2 * C_OUT + C_OUT + t];
        }
        const float inv_m = 1.0f / (float)M;
        const float mean = s * inv_m;
        const float var  = fmaf(-mean, mean, s2 * inv_m);
        const float scv  = gamma[t] * rsqrtf(var + BN_EPS);
        sc[t] = scv;
        sh[t] = fmaf(-mean, scv, beta[t]);
    }
    if (blockIdx.x == 0 && t == 0) no_out[0] = (float)M;
    __syncthreads();

    const size_t total4 = (size_t)M * C_OUT / 4;
    float4* h4 = (float4*)h;
    for (size_t i = (size_t)blockIdx.x * blockDim.x + t;
         i < total4; i += (size_t)gridDim.x * blockDim.x) {
        float4 v = h4[i];
        const int c = (int)((i * 4) & (C_OUT - 1));
        v.x = fmaxf(fmaf(v.x, sc[c+0], sh[c+0]), 0.f);
        v.y = fmaxf(fmaf(v.y, sc[c+1], sh[c+1]), 0.f);
        v.z = fmaxf(fmaf(v.z, sc[c+2], sh[c+2]), 0.f);
        v.w = fmaxf(fmaf(v.w, sc[c+3], sh[c+3]), 0.f);
        h4[i] = v;
    }
}

extern "C" void kernel_launch(void* const* d_in, const int* in_sizes, int n_in,
                              void* d_out, int out_size, void* d_ws, size_t ws_size,
                              hipStream_t stream)
{
    const float* p     = (const float*)d_in[0];
    const float* x     = (const float*)d_in[1];
    // d_in[2] = o (unused)
    const int*   idx   = (const int*)d_in[3];
    const int*   knn   = (const int*)d_in[4];
    const float* W     = (const float*)d_in[5];
    const float* bias  = (const float*)d_in[6];
    const float* gamma = (const float*)d_in[7];
    const float* beta  = (const float*)d_in[8];

    const int N = in_sizes[1] / C_IN;  // 262144
    const int M = in_sizes[3];         // 65536

    float* out    = (float*)d_out;
    float* np_out = out;                                     // [M,3]
    float* h      = out + (size_t)M * 3;                     // [M,128]
    float* no_out = out + (size_t)M * 3 + (size_t)M * C_OUT; // [1]

    const size_t xq_bytes = (size_t)N * C_IN;                // 16 MB fp8 table
    const bool   fp8_path = ws_size >= xq_bytes + 2048;

    const size_t tail = fp8_path ? (ws_size - xq_bytes) : ws_size;
    int rep = 1;
    while (rep < 8 && (size_t)(2 * rep) * 2 * C_OUT * sizeof(float) <= tail)
        rep <<= 1;

    float* gsum = fp8_path ? (float*)((char*)d_ws + xq_bytes) : (float*)d_ws;
    const unsigned rep_mask = (unsigned)(rep - 1);

    if (fp8_path) {
        uint4* xq = (uint4*)d_ws;
        const int n16 = N * C_IN / 16;
        sa_cvt   <<<2048, 256, 0, stream>>>((const float4*)x, xq, n16,
                                            gsum, rep * 2 * C_OUT);
        sa_pool_h<<<M / 8, 256, 0, stream>>>(p, (const uint2*)d_ws, idx, knn, np_out, h);
    } else {
        sa_zero  <<<1, 256, 0, stream>>>(gsum, rep * 2 * C_OUT);
        sa_pool_f<<<M / 4, 256, 0, stream>>>(p, x, idx, knn, np_out, h);
    }

    sa_gemm_mfma <<<M / TILE, 256, 0, stream>>>(W, bias, h, gsum, rep_mask);
    sa_bnrelu_fin<<<1024,     256, 0, stream>>>(h, gsum, gamma, beta, no_out, M, rep);
}